// Round 1
// 1674.700 us; speedup vs baseline: 1.1238x; 1.1238x over previous
//
#include <hip/hip_runtime.h>
#include <cstddef>

// ---------------------------------------------------------------------------
// RSSM observe. R3: MFMA-fragment-ordered weights (coalesced B loads).
//   K0: weight convert/transpose to bf16. All K2 weight matrices are stored
//       in MFMA fragment order: frag[tile][k][lane][8] so that each
//       bf16x8 B-fragment load is one fully-coalesced 1KB transaction
//       (previously lanes strode 448B -> 64 cachelines per load; K2 was
//       VMEM-transaction-bound at ~54k cycles/step).
//   K1: embed-part of obs1 precomputed as bf16 MFMA GEMM (unchanged).
//   K2: 64 blocks x 16 batch rows x 512 threads (8 waves). All dense layers
//       via mfma_f32_16x16x32_bf16, M=16 (one m-tile). B-fragments streamed
//       from L2-resident global weights in fragment order.
//
// ws layout (bf16 elements unless noted):
//   [0,       212992)  k1wT   [208][1024]          (K1 B operand, row-major)
//   [212992,  226304)  w1F    [13][2][64][8]       (img1, K-pad to 64)
//   [226304,  362496)  gwF    [38][7][64][8]       (gru_w, K-pad to 224)
//   [362496,  498688)  guF    [38][7][64][8]       (gru_u)
//   [498688,  591872)  wcF    [26][7][64][8]       (img2 tiles 0..12, obs1-deter 13..25)
//   [591872,  620544)  whF    [8][7][64][8]        (omean/ostd/imean/istd heads)
//   bytes [1241088, +52428800) xpre fp32 [64][1024][200]
// ---------------------------------------------------------------------------

typedef __bf16 bf16x8 __attribute__((ext_vector_type(8)));
typedef float  f32x4  __attribute__((ext_vector_type(4)));

#define OFF_K1WT 0
#define OFF_W1F  212992
#define OFF_GWF  226304
#define OFF_GUF  362496
#define OFF_WCF  498688
#define OFF_WHF  591872
#define WS_BF_TOTAL 620544
#define WS_XPRE_BYTES 1241088   // WS_BF_TOTAL * 2

__device__ __forceinline__ float elu1(float v){ return v > 0.f ? v : expm1f(v); }
__device__ __forceinline__ float sigm(float v){ return 1.f / (1.f + expf(-v)); }
__device__ __forceinline__ float spls(float v){ return fmaxf(v,0.f) + log1pf(expf(-fabsf(v))); }

// ---------------------------------------------------------------------------
// K0: weight conversion into MFMA fragment order.
// Fragment element (tile tt, frag k, lane, e) = W[kk][n] with
//   n  = tt*16 + (lane&15)            (output column)
//   kk = k*32 + (lane>>4)*8 + e       (reduction index)
// Zero-padded outside the valid (n, kk) range.
// ---------------------------------------------------------------------------
__global__ __launch_bounds__(256) void k0_convert(
    const float* __restrict__ w_img1, const float* __restrict__ gru_w,
    const float* __restrict__ gru_u,  const float* __restrict__ w_img2,
    const float* __restrict__ w_imean, const float* __restrict__ w_istd,
    const float* __restrict__ w_obs1, const float* __restrict__ w_omean,
    const float* __restrict__ w_ostd, __bf16* __restrict__ o)
{
  int i = blockIdx.x * 256 + threadIdx.x;
  if (i >= WS_BF_TOTAL) return;
  float v = 0.f;
  if (i < OFF_W1F) {                       // k1wT[n][k] = w_obs1[200+k][n]
    int n = i >> 10, k = i & 1023;
    v = (n < 200) ? w_obs1[(size_t)(200 + k) * 200 + n] : 0.f;
  } else if (i < OFF_GWF) {                // w1F: [13][2][64][8]
    int q = i - OFF_W1F;
    int e = q & 7, lane = (q >> 3) & 63, f = q >> 9;
    int kc = f & 1, tt = f >> 1;
    int n  = tt * 16 + (lane & 15);
    int kk = kc * 32 + (lane >> 4) * 8 + e;
    if (n < 200 && kk < 36) v = w_img1[kk * 200 + n];
  } else if (i < OFF_GUF) {                // gwF: [38][7][64][8]
    int q = i - OFF_GWF;
    int e = q & 7, lane = (q >> 3) & 63, f = q >> 9;
    int k = f % 7, tt = f / 7;
    int j  = tt * 16 + (lane & 15);
    int kk = k * 32 + (lane >> 4) * 8 + e;
    if (j < 600 && kk < 200) v = gru_w[kk * 600 + j];
  } else if (i < OFF_WCF) {                // guF: [38][7][64][8]
    int q = i - OFF_GUF;
    int e = q & 7, lane = (q >> 3) & 63, f = q >> 9;
    int k = f % 7, tt = f / 7;
    int j  = tt * 16 + (lane & 15);
    int kk = k * 32 + (lane >> 4) * 8 + e;
    if (j < 600 && kk < 200) v = gru_u[kk * 600 + j];
  } else if (i < OFF_WHF) {                // wcF: [26][7][64][8]
    int q = i - OFF_WCF;
    int e = q & 7, lane = (q >> 3) & 63, f = q >> 9;
    int k = f % 7, tt = f / 7;
    int kk = k * 32 + (lane >> 4) * 8 + e;
    if (kk < 200) {
      if (tt < 13) {
        int n = tt * 16 + (lane & 15);
        if (n < 200) v = w_img2[kk * 200 + n];
      } else {
        int n = (tt - 13) * 16 + (lane & 15);
        if (n < 200) v = w_obs1[kk * 200 + n];
      }
    }
  } else {                                 // whF: [8][7][64][8], heads 32 cols each
    int q = i - OFF_WHF;
    int e = q & 7, lane = (q >> 3) & 63, f = q >> 9;
    int k = f % 7, tt = f / 7;
    int kk = k * 32 + (lane >> 4) * 8 + e;
    int n = tt * 16 + (lane & 15);
    int h = n >> 5, c = n & 31;
    if (kk < 200 && c < 30) {
      const float* wh = (h == 0) ? w_omean : (h == 1) ? w_ostd : (h == 2) ? w_imean : w_istd;
      v = wh[kk * 30 + c];
    }
  }
  o[i] = (__bf16)v;
}

// ---------------------------------------------------------------------------
// K1: xpre[t][b][h] = embed[b*64+t,:] @ w_obs1[200:1224,:] + b_obs1  (as R1)
// ---------------------------------------------------------------------------
__global__ __launch_bounds__(256) void k1_embed_gemm(
    const float* __restrict__ embed, const __bf16* __restrict__ wT,
    const float* __restrict__ b_obs1, float* __restrict__ xpre)
{
  __shared__ __align__(16) __bf16 As[64][72];
  __shared__ __align__(16) __bf16 Bs[208][72];
  int tid = threadIdx.x;
  int b = blockIdx.x;
  int wave = tid >> 6, lane = tid & 63;
  int lm = lane & 15, quad = lane >> 4;

  f32x4 acc[13];
#pragma unroll
  for (int n = 0; n < 13; ++n) acc[n] = (f32x4){0.f, 0.f, 0.f, 0.f};

  const float* arow_base = embed + (size_t)b * 64 * 1024;

  for (int ko = 0; ko < 1024; ko += 64) {
#pragma unroll
    for (int p = 0; p < 4; ++p) {
      int v = p * 256 + tid; int row = v >> 4; int c4 = v & 15;
      float4 f = *(const float4*)(arow_base + (size_t)row * 1024 + ko + c4 * 4);
      __bf16* dst = &As[row][c4 * 4];
      dst[0] = (__bf16)f.x; dst[1] = (__bf16)f.y;
      dst[2] = (__bf16)f.z; dst[3] = (__bf16)f.w;
    }
#pragma unroll
    for (int p = 0; p < 13; ++p) {
      int v = p * 256 + tid; int n = v >> 4; int c4 = v & 15;
      ushort4 u = *(const ushort4*)(wT + (size_t)n * 1024 + ko + c4 * 4);
      *(ushort4*)&Bs[n][c4 * 4] = u;
    }
    __syncthreads();
#pragma unroll
    for (int kc = 0; kc < 2; ++kc) {
      bf16x8 a = *(const bf16x8*)&As[16 * wave + lm][kc * 32 + quad * 8];
#pragma unroll
      for (int n = 0; n < 13; ++n) {
        bf16x8 bb = *(const bf16x8*)&Bs[16 * n + lm][kc * 32 + quad * 8];
        acc[n] = __builtin_amdgcn_mfma_f32_16x16x32_bf16(a, bb, acc[n], 0, 0, 0);
      }
    }
    __syncthreads();
  }
  int trow_base = 16 * wave + quad * 4;
#pragma unroll
  for (int n = 0; n < 13; ++n) {
    int col = n * 16 + lm;
    if (col < 200) {
      float bias = b_obs1[col];
#pragma unroll
      for (int r = 0; r < 4; ++r) {
        int trow = trow_base + r;
        xpre[(size_t)trow * (1024 * 200) + (size_t)b * 200 + col] = acc[n][r] + bias;
      }
    }
  }
}

// ---------------------------------------------------------------------------
// K2: MFMA recurrent kernel.  64 blocks x 512 threads, 16 batch rows/block.
// Weight fragments: one coalesced 1KB load per bf16x8 (lane*8 layout).
// ---------------------------------------------------------------------------
__global__ __launch_bounds__(512) void k2_recurrent(
    const float* __restrict__ action, const float* __restrict__ noise_prior,
    const float* __restrict__ noise_post,
    const float* __restrict__ b_img1, const float* __restrict__ gru_b,
    const float* __restrict__ gru_rb, const float* __restrict__ b_img2,
    const float* __restrict__ b_imean, const float* __restrict__ b_istd,
    const float* __restrict__ b_omean, const float* __restrict__ b_ostd,
    const __bf16* __restrict__ w1F, const __bf16* __restrict__ gwF,
    const __bf16* __restrict__ guF, const __bf16* __restrict__ wcF,
    const __bf16* __restrict__ whF,
    const float* __restrict__ xpre, float* __restrict__ out)
{
  // A-operand buffers: row stride chosen for 16B alignment + <=2-way banks.
  __shared__ __align__(16) __bf16 actin[16][72];   // [stoch(30)|action(6)|pad->64|slack]
  __shared__ __align__(16) __bf16 xbuf[16][232];   // x (img1 out), K-pad 200..223 = 0
  __shared__ __align__(16) __bf16 dbuf[16][232];   // deter carry (bf16)
  __shared__ __align__(16) char   ovl[39168];      // ggbuf bf16[16][1224]  OR  {x2b,xob,[16][132]f32 headbuf}
  __shared__ float biasL[1760];  // [0:208) img1 | [208:816) gru_b | [816:1424) gru_rb | [1424:1632) img2 | [1632:1760) heads

  const int tid  = threadIdx.x;
  const int wv   = tid >> 6;
  const int lane = tid & 63;
  const int lm   = lane & 15, quad = lane >> 4;
  const int b0   = blockIdx.x * 16;

  __bf16* gg    = (__bf16*)ovl;                 // stride 1224
  __bf16* x2b   = (__bf16*)ovl;                 // stride 232
  __bf16* xob   = (__bf16*)(ovl + 7424);        // stride 232
  float*  headb = (float*)(ovl + 14848);        // stride 132

  // ---- init: zero A-buffers (incl. K-pads), load biases, load action[0]
  for (int i = tid; i < 16 * 72; i += 512) {
    int m = i / 72, c = i - m * 72;
    if (c < 30 || c >= 36) actin[m][c] = (__bf16)0.f;
  }
  for (int i = tid; i < 16 * 232; i += 512) { ((__bf16*)xbuf)[i] = (__bf16)0.f; ((__bf16*)dbuf)[i] = (__bf16)0.f; }
  for (int i = tid; i < 1760; i += 512) {
    float v = 0.f;
    if (i < 208)       { if (i < 200) v = b_img1[i]; }
    else if (i < 816)  { int j = i - 208;  if (j < 600) v = gru_b[j]; }
    else if (i < 1424) { int j = i - 816;  if (j < 600) v = gru_rb[j]; }
    else if (i < 1632) { int j = i - 1424; if (j < 200) v = b_img2[j]; }
    else { int n = i - 1632; int h = n >> 5, c = n & 31;
           if (c < 30) v = ((h == 0) ? b_omean : (h == 1) ? b_ostd : (h == 2) ? b_imean : b_istd)[c]; }
    biasL[i] = v;
  }
  if (tid < 96) {
    int m = tid / 6, k = tid - m * 6;
    actin[m][30 + k] = (__bf16)action[(size_t)(b0 + m) * 384 + k];
  }
  __syncthreads();

  for (int t = 0; t < 64; ++t) {
    // ---- phase A: x = elu([stoch,a] @ w_img1 + b)   (13 n-tiles, K=64)
    for (int tt = wv; tt < 13; tt += 8) {
      const __bf16* bw = w1F + tt * 1024 + lane * 8;
      bf16x8 a0 = *(const bf16x8*)&actin[lm][quad * 8];
      bf16x8 a1 = *(const bf16x8*)&actin[lm][32 + quad * 8];
      bf16x8 bv0 = *(const bf16x8*)(bw);
      bf16x8 bv1 = *(const bf16x8*)(bw + 512);
      f32x4 c = (f32x4){0.f, 0.f, 0.f, 0.f};
      c = __builtin_amdgcn_mfma_f32_16x16x32_bf16(a0, bv0, c, 0, 0, 0);
      c = __builtin_amdgcn_mfma_f32_16x16x32_bf16(a1, bv1, c, 0, 0, 0);
      int col = tt * 16 + lm;
      float bias = biasL[col];
      if (col < 200) {
#pragma unroll
        for (int r = 0; r < 4; ++r) xbuf[quad * 4 + r][col] = (__bf16)elu1(c[r] + bias);
      }
    }
    __syncthreads();  // S2

    // ---- phase B: waves 0..3: xg = x@gru_w ; waves 4..7: hg = deter@gru_u
    {
      const int gsel = wv >> 2, wsub = wv & 3;
      const __bf16* WF    = gsel ? guF : gwF;
      const __bf16* Abase = gsel ? &dbuf[0][0] : &xbuf[0][0];
      const int cbase = gsel ? 608 : 0;
      const int bbase = gsel ? 816 : 208;
      bf16x8 af[7];
#pragma unroll
      for (int k = 0; k < 7; ++k) af[k] = *(const bf16x8*)(Abase + lm * 232 + k * 32 + quad * 8);
      for (int tt = wsub; tt < 38; tt += 4) {
        const __bf16* bw = WF + tt * 3584 + lane * 8;
        f32x4 c = (f32x4){0.f, 0.f, 0.f, 0.f};
#pragma unroll
        for (int k = 0; k < 7; ++k) {
          bf16x8 bv = *(const bf16x8*)(bw + k * 512);
          c = __builtin_amdgcn_mfma_f32_16x16x32_bf16(af[k], bv, c, 0, 0, 0);
        }
        int col = tt * 16 + lm;
        float bias = biasL[bbase + col];
#pragma unroll
        for (int r = 0; r < 4; ++r) gg[(quad * 4 + r) * 1224 + cbase + col] = (__bf16)(c[r] + bias);
      }
    }
    __syncthreads();  // S3

    // ---- phase C1: GRU combine -> deter (bf16 carry) + out
    for (int idx = tid; idx < 3200; idx += 512) {
      int m = idx / 200, d = idx - m * 200;
      const __bf16* row = gg + m * 1224;
      float xz = (float)row[d],        xr_ = (float)row[200 + d], xh = (float)row[400 + d];
      float hz = (float)row[608 + d],  hr_ = (float)row[808 + d], hh = (float)row[1008 + d];
      float z  = sigm(xz + hz);
      float rr = sigm(xr_ + hr_);
      float hc = tanhf(xh + rr * hh);
      float dn = z * (float)dbuf[m][d] + (1.f - z) * hc;
      dbuf[m][d] = (__bf16)dn;
      size_t ob = ((size_t)(b0 + m) * 64 + t) * 580;
      out[ob + 90 + d]  = dn;
      out[ob + 380 + d] = dn;
    }
    __syncthreads();  // S4

    // ---- phase C2: x2 = elu(d@w_img2+b) ; xo = elu(d@w_obs1_d + xpre)
    {
      bf16x8 df[7];
#pragma unroll
      for (int k = 0; k < 7; ++k) df[k] = *(const bf16x8*)(&dbuf[lm][0] + k * 32 + quad * 8);
      for (int tt = wv; tt < 26; tt += 8) {
        const __bf16* bw = wcF + tt * 3584 + lane * 8;
        f32x4 c = (f32x4){0.f, 0.f, 0.f, 0.f};
#pragma unroll
        for (int k = 0; k < 7; ++k) {
          bf16x8 bv = *(const bf16x8*)(bw + k * 512);
          c = __builtin_amdgcn_mfma_f32_16x16x32_bf16(df[k], bv, c, 0, 0, 0);
        }
        if (tt < 13) {
          int col = tt * 16 + lm;
          float bias = biasL[1424 + col];
          if (col < 200) {
#pragma unroll
            for (int r = 0; r < 4; ++r) x2b[(quad * 4 + r) * 232 + col] = (__bf16)elu1(c[r] + bias);
          }
        } else {
          int col = (tt - 13) * 16 + lm;
          if (col < 200) {
#pragma unroll
            for (int r = 0; r < 4; ++r) {
              int m2 = quad * 4 + r;
              float pre = c[r] + xpre[((size_t)t * 1024 + b0 + m2) * 200 + col];
              xob[m2 * 232 + col] = (__bf16)elu1(pre);
            }
          }
        }
      }
    }
    __syncthreads();  // S5

    // ---- phase D: heads.  wave wv handles tile wv; tiles 0..3 <- xo, 4..7 <- x2
    {
      const __bf16* Ab = (wv < 4) ? xob : x2b;
      bf16x8 hf[7];
#pragma unroll
      for (int k = 0; k < 7; ++k) hf[k] = *(const bf16x8*)(Ab + lm * 232 + k * 32 + quad * 8);
      const __bf16* bw = whF + wv * 3584 + lane * 8;
      f32x4 c = (f32x4){0.f, 0.f, 0.f, 0.f};
#pragma unroll
      for (int k = 0; k < 7; ++k) {
        bf16x8 bv = *(const bf16x8*)(bw + k * 512);
        c = __builtin_amdgcn_mfma_f32_16x16x32_bf16(hf[k], bv, c, 0, 0, 0);
      }
      int n = wv * 16 + lm;
      float bias = biasL[1632 + n];
#pragma unroll
      for (int r = 0; r < 4; ++r) headb[(quad * 4 + r) * 132 + n] = c[r] + bias;
    }
    __syncthreads();  // S6

    // ---- phase E: nonlinearities + sample + outputs + next stoch/action
    if (tid < 480) {
      int m = tid / 30, c = tid - m * 30;
      const float* hb = headb + m * 132;
      float om = hb[c], osr = hb[32 + c], pm = hb[64 + c], psr = hb[96 + c];
      float os = spls(osr);               // obs: no +0.1
      float ps = spls(psr) + 0.1f;        // img: +0.1
      float nzo = noise_post [(size_t)t * 30720 + (b0 + m) * 30 + c];
      float nzp = noise_prior[(size_t)t * 30720 + (b0 + m) * 30 + c];
      float ost = om + os * nzo;
      float pst = pm + ps * nzp;
      actin[m][c] = (__bf16)ost;          // next stoch (bf16 carry)
      size_t ob = ((size_t)(b0 + m) * 64 + t) * 580;
      out[ob + c]       = om;
      out[ob + 30 + c]  = os;
      out[ob + 60 + c]  = ost;
      out[ob + 290 + c] = pm;
      out[ob + 320 + c] = ps;
      out[ob + 350 + c] = pst;
    } else if (t < 63) {
      for (int j = tid - 480; j < 96; j += 32) {
        int m = j / 6, k = j - m * 6;
        actin[m][30 + k] = (__bf16)action[(size_t)(b0 + m) * 384 + (t + 1) * 6 + k];
      }
    }
    __syncthreads();  // S7
  }
}

// ---------------------------------------------------------------------------
extern "C" void kernel_launch(void* const* d_in, const int* in_sizes, int n_in,
                              void* d_out, int out_size, void* d_ws, size_t ws_size,
                              hipStream_t stream) {
  const float* embed   = (const float*)d_in[0];
  const float* action  = (const float*)d_in[1];
  const float* nzp     = (const float*)d_in[2];
  const float* nzo     = (const float*)d_in[3];
  const float* w_img1  = (const float*)d_in[4];
  const float* b_img1  = (const float*)d_in[5];
  const float* gru_w   = (const float*)d_in[6];
  const float* gru_u   = (const float*)d_in[7];
  const float* gru_b   = (const float*)d_in[8];
  const float* gru_rb  = (const float*)d_in[9];
  const float* w_img2  = (const float*)d_in[10];
  const float* b_img2  = (const float*)d_in[11];
  const float* w_imean = (const float*)d_in[12];
  const float* b_imean = (const float*)d_in[13];
  const float* w_istd  = (const float*)d_in[14];
  const float* b_istd  = (const float*)d_in[15];
  const float* w_obs1  = (const float*)d_in[16];
  const float* b_obs1  = (const float*)d_in[17];
  const float* w_omean = (const float*)d_in[18];
  const float* b_omean = (const float*)d_in[19];
  const float* w_ostd  = (const float*)d_in[20];
  const float* b_ostd  = (const float*)d_in[21];
  float* out = (float*)d_out;

  __bf16* wbf = (__bf16*)d_ws;
  float* xpre = (float*)((char*)d_ws + WS_XPRE_BYTES);

  k0_convert<<<(WS_BF_TOTAL + 255) / 256, 256, 0, stream>>>(
      w_img1, gru_w, gru_u, w_img2, w_imean, w_istd, w_obs1, w_omean, w_ostd, wbf);

  k1_embed_gemm<<<1024, 256, 0, stream>>>(embed, wbf + OFF_K1WT, b_obs1, xpre);

  k2_recurrent<<<64, 512, 0, stream>>>(
      action, nzp, nzo,
      b_img1, gru_b, gru_rb, b_img2, b_imean, b_istd, b_omean, b_ostd,
      wbf + OFF_W1F, wbf + OFF_GWF, wbf + OFF_GUF, wbf + OFF_WCF, wbf + OFF_WHF,
      xpre, out);
}

// Round 2
// 1516.865 us; speedup vs baseline: 1.2407x; 1.1041x over previous
//
#include <hip/hip_runtime.h>
#include <cstddef>

// ---------------------------------------------------------------------------
// RSSM observe. R4: 16-wave K2 (1024 threads) for latency hiding.
//   K0: weight convert into MFMA fragment order (unchanged from R3).
//   K1: embed-part of obs1 precomputed as bf16 MFMA GEMM (unchanged).
//   K2: 64 blocks x 16 batch rows x 1024 threads (16 waves, 4/SIMD).
//       Per-wave N-tile counts halved vs R3 (phase B 5 tiles, C2 2, A 1).
//       Phase B double-buffers B-fragments across tiles (no per-tile vmcnt
//       stall); MFMA accumulator chains split in two; xpre prefetched into
//       regs during phase B; noise staged to LDS by phase-A-idle waves.
//
// ws layout (bf16 elements unless noted):
//   [0,       212992)  k1wT   [208][1024]          (K1 B operand, row-major)
//   [212992,  226304)  w1F    [13][2][64][8]       (img1, K-pad to 64)
//   [226304,  362496)  gwF    [38][7][64][8]       (gru_w, K-pad to 224)
//   [362496,  498688)  guF    [38][7][64][8]       (gru_u)
//   [498688,  591872)  wcF    [26][7][64][8]       (img2 tiles 0..12, obs1-deter 13..25)
//   [591872,  620544)  whF    [8][7][64][8]        (omean/ostd/imean/istd heads)
//   bytes [1241088, +52428800) xpre fp32 [64][1024][200]
// ---------------------------------------------------------------------------

typedef __bf16 bf16x8 __attribute__((ext_vector_type(8)));
typedef float  f32x4  __attribute__((ext_vector_type(4)));

#define OFF_K1WT 0
#define OFF_W1F  212992
#define OFF_GWF  226304
#define OFF_GUF  362496
#define OFF_WCF  498688
#define OFF_WHF  591872
#define WS_BF_TOTAL 620544
#define WS_XPRE_BYTES 1241088   // WS_BF_TOTAL * 2

__device__ __forceinline__ float elu1(float v){ return v > 0.f ? v : expm1f(v); }
__device__ __forceinline__ float sigm(float v){ return 1.f / (1.f + expf(-v)); }
__device__ __forceinline__ float spls(float v){ return fmaxf(v,0.f) + log1pf(expf(-fabsf(v))); }

// ---------------------------------------------------------------------------
// K0: weight conversion into MFMA fragment order.
// Fragment element (tile tt, frag k, lane, e) = W[kk][n] with
//   n  = tt*16 + (lane&15)            (output column)
//   kk = k*32 + (lane>>4)*8 + e       (reduction index)
// Zero-padded outside the valid (n, kk) range.
// ---------------------------------------------------------------------------
__global__ __launch_bounds__(256) void k0_convert(
    const float* __restrict__ w_img1, const float* __restrict__ gru_w,
    const float* __restrict__ gru_u,  const float* __restrict__ w_img2,
    const float* __restrict__ w_imean, const float* __restrict__ w_istd,
    const float* __restrict__ w_obs1, const float* __restrict__ w_omean,
    const float* __restrict__ w_ostd, __bf16* __restrict__ o)
{
  int i = blockIdx.x * 256 + threadIdx.x;
  if (i >= WS_BF_TOTAL) return;
  float v = 0.f;
  if (i < OFF_W1F) {                       // k1wT[n][k] = w_obs1[200+k][n]
    int n = i >> 10, k = i & 1023;
    v = (n < 200) ? w_obs1[(size_t)(200 + k) * 200 + n] : 0.f;
  } else if (i < OFF_GWF) {                // w1F: [13][2][64][8]
    int q = i - OFF_W1F;
    int e = q & 7, lane = (q >> 3) & 63, f = q >> 9;
    int kc = f & 1, tt = f >> 1;
    int n  = tt * 16 + (lane & 15);
    int kk = kc * 32 + (lane >> 4) * 8 + e;
    if (n < 200 && kk < 36) v = w_img1[kk * 200 + n];
  } else if (i < OFF_GUF) {                // gwF: [38][7][64][8]
    int q = i - OFF_GWF;
    int e = q & 7, lane = (q >> 3) & 63, f = q >> 9;
    int k = f % 7, tt = f / 7;
    int j  = tt * 16 + (lane & 15);
    int kk = k * 32 + (lane >> 4) * 8 + e;
    if (j < 600 && kk < 200) v = gru_w[kk * 600 + j];
  } else if (i < OFF_WCF) {                // guF: [38][7][64][8]
    int q = i - OFF_GUF;
    int e = q & 7, lane = (q >> 3) & 63, f = q >> 9;
    int k = f % 7, tt = f / 7;
    int j  = tt * 16 + (lane & 15);
    int kk = k * 32 + (lane >> 4) * 8 + e;
    if (j < 600 && kk < 200) v = gru_u[kk * 600 + j];
  } else if (i < OFF_WHF) {                // wcF: [26][7][64][8]
    int q = i - OFF_WCF;
    int e = q & 7, lane = (q >> 3) & 63, f = q >> 9;
    int k = f % 7, tt = f / 7;
    int kk = k * 32 + (lane >> 4) * 8 + e;
    if (kk < 200) {
      if (tt < 13) {
        int n = tt * 16 + (lane & 15);
        if (n < 200) v = w_img2[kk * 200 + n];
      } else {
        int n = (tt - 13) * 16 + (lane & 15);
        if (n < 200) v = w_obs1[kk * 200 + n];
      }
    }
  } else {                                 // whF: [8][7][64][8], heads 32 cols each
    int q = i - OFF_WHF;
    int e = q & 7, lane = (q >> 3) & 63, f = q >> 9;
    int k = f % 7, tt = f / 7;
    int kk = k * 32 + (lane >> 4) * 8 + e;
    int n = tt * 16 + (lane & 15);
    int h = n >> 5, c = n & 31;
    if (kk < 200 && c < 30) {
      const float* wh = (h == 0) ? w_omean : (h == 1) ? w_ostd : (h == 2) ? w_imean : w_istd;
      v = wh[kk * 30 + c];
    }
  }
  o[i] = (__bf16)v;
}

// ---------------------------------------------------------------------------
// K1: xpre[t][b][h] = embed[b*64+t,:] @ w_obs1[200:1224,:] + b_obs1  (as R1)
// ---------------------------------------------------------------------------
__global__ __launch_bounds__(256) void k1_embed_gemm(
    const float* __restrict__ embed, const __bf16* __restrict__ wT,
    const float* __restrict__ b_obs1, float* __restrict__ xpre)
{
  __shared__ __align__(16) __bf16 As[64][72];
  __shared__ __align__(16) __bf16 Bs[208][72];
  int tid = threadIdx.x;
  int b = blockIdx.x;
  int wave = tid >> 6, lane = tid & 63;
  int lm = lane & 15, quad = lane >> 4;

  f32x4 acc[13];
#pragma unroll
  for (int n = 0; n < 13; ++n) acc[n] = (f32x4){0.f, 0.f, 0.f, 0.f};

  const float* arow_base = embed + (size_t)b * 64 * 1024;

  for (int ko = 0; ko < 1024; ko += 64) {
#pragma unroll
    for (int p = 0; p < 4; ++p) {
      int v = p * 256 + tid; int row = v >> 4; int c4 = v & 15;
      float4 f = *(const float4*)(arow_base + (size_t)row * 1024 + ko + c4 * 4);
      __bf16* dst = &As[row][c4 * 4];
      dst[0] = (__bf16)f.x; dst[1] = (__bf16)f.y;
      dst[2] = (__bf16)f.z; dst[3] = (__bf16)f.w;
    }
#pragma unroll
    for (int p = 0; p < 13; ++p) {
      int v = p * 256 + tid; int n = v >> 4; int c4 = v & 15;
      ushort4 u = *(const ushort4*)(wT + (size_t)n * 1024 + ko + c4 * 4);
      *(ushort4*)&Bs[n][c4 * 4] = u;
    }
    __syncthreads();
#pragma unroll
    for (int kc = 0; kc < 2; ++kc) {
      bf16x8 a = *(const bf16x8*)&As[16 * wave + lm][kc * 32 + quad * 8];
#pragma unroll
      for (int n = 0; n < 13; ++n) {
        bf16x8 bb = *(const bf16x8*)&Bs[16 * n + lm][kc * 32 + quad * 8];
        acc[n] = __builtin_amdgcn_mfma_f32_16x16x32_bf16(a, bb, acc[n], 0, 0, 0);
      }
    }
    __syncthreads();
  }
  int trow_base = 16 * wave + quad * 4;
#pragma unroll
  for (int n = 0; n < 13; ++n) {
    int col = n * 16 + lm;
    if (col < 200) {
      float bias = b_obs1[col];
#pragma unroll
      for (int r = 0; r < 4; ++r) {
        int trow = trow_base + r;
        xpre[(size_t)trow * (1024 * 200) + (size_t)b * 200 + col] = acc[n][r] + bias;
      }
    }
  }
}

// ---------------------------------------------------------------------------
// K2: MFMA recurrent kernel.  64 blocks x 1024 threads (16 waves), 16 rows.
// ---------------------------------------------------------------------------
__global__ __launch_bounds__(1024) void k2_recurrent(
    const float* __restrict__ action, const float* __restrict__ noise_prior,
    const float* __restrict__ noise_post,
    const float* __restrict__ b_img1, const float* __restrict__ gru_b,
    const float* __restrict__ gru_rb, const float* __restrict__ b_img2,
    const float* __restrict__ b_imean, const float* __restrict__ b_istd,
    const float* __restrict__ b_omean, const float* __restrict__ b_ostd,
    const __bf16* __restrict__ w1F, const __bf16* __restrict__ gwF,
    const __bf16* __restrict__ guF, const __bf16* __restrict__ wcF,
    const __bf16* __restrict__ whF,
    const float* __restrict__ xpre, float* __restrict__ out)
{
  __shared__ __align__(16) __bf16 actin[16][72];   // [stoch(30)|action(6)|pad->64|slack]
  __shared__ __align__(16) __bf16 xbuf[16][232];   // x (img1 out), K-pad 200..223 = 0
  __shared__ __align__(16) __bf16 dbuf[16][232];   // deter carry (bf16)
  __shared__ __align__(16) char   ovl[39168];      // ggbuf bf16[16][1224] OR {x2b,xob,headb}
  __shared__ float biasL[1760];
  __shared__ float noiseb[960];                    // [0:480) post | [480:960) prior

  const int tid  = threadIdx.x;
  const int wv   = tid >> 6;
  const int lane = tid & 63;
  const int lm   = lane & 15, quad = lane >> 4;
  const int b0   = blockIdx.x * 16;

  __bf16* gg    = (__bf16*)ovl;                 // stride 1224
  __bf16* x2b   = (__bf16*)ovl;                 // stride 232
  __bf16* xob   = (__bf16*)(ovl + 7424);        // stride 232
  float*  headb = (float*)(ovl + 14848);        // stride 132

  // ---- init
  for (int i = tid; i < 16 * 72; i += 1024) {
    int m = i / 72, c = i - m * 72;
    if (c < 30 || c >= 36) actin[m][c] = (__bf16)0.f;
  }
  for (int i = tid; i < 16 * 232; i += 1024) { ((__bf16*)xbuf)[i] = (__bf16)0.f; ((__bf16*)dbuf)[i] = (__bf16)0.f; }
  for (int i = tid; i < 1760; i += 1024) {
    float v = 0.f;
    if (i < 208)       { if (i < 200) v = b_img1[i]; }
    else if (i < 816)  { int j = i - 208;  if (j < 600) v = gru_b[j]; }
    else if (i < 1424) { int j = i - 816;  if (j < 600) v = gru_rb[j]; }
    else if (i < 1632) { int j = i - 1424; if (j < 200) v = b_img2[j]; }
    else { int n = i - 1632; int h = n >> 5, c = n & 31;
           if (c < 30) v = ((h == 0) ? b_omean : (h == 1) ? b_ostd : (h == 2) ? b_imean : b_istd)[c]; }
    biasL[i] = v;
  }
  if (tid < 96) {
    int m = tid / 6, k = tid - m * 6;
    actin[m][30 + k] = (__bf16)action[(size_t)(b0 + m) * 384 + k];
  }
  __syncthreads();

  for (int t = 0; t < 64; ++t) {
    // ---- phase A: x = elu([stoch,a] @ w_img1 + b).  Waves 0..12: one tile
    //      each.  Waves 13..15: stage this step's noise into LDS (covers the
    //      ~900cyc HBM latency before phase E).
    if (wv < 13) {
      const __bf16* bw = w1F + wv * 1024 + lane * 8;
      bf16x8 a0 = *(const bf16x8*)&actin[lm][quad * 8];
      bf16x8 a1 = *(const bf16x8*)&actin[lm][32 + quad * 8];
      bf16x8 bv0 = *(const bf16x8*)(bw);
      bf16x8 bv1 = *(const bf16x8*)(bw + 512);
      f32x4 c = (f32x4){0.f, 0.f, 0.f, 0.f};
      c = __builtin_amdgcn_mfma_f32_16x16x32_bf16(a0, bv0, c, 0, 0, 0);
      c = __builtin_amdgcn_mfma_f32_16x16x32_bf16(a1, bv1, c, 0, 0, 0);
      int col = wv * 16 + lm;
      float bias = biasL[col];
      if (col < 200) {
#pragma unroll
        for (int r = 0; r < 4; ++r) xbuf[quad * 4 + r][col] = (__bf16)elu1(c[r] + bias);
      }
    } else {
      int j = (wv - 13) * 64 + lane;         // 0..191
      const float* np = noise_post  + (size_t)t * 30720 + (size_t)b0 * 30;
      const float* nq = noise_prior + (size_t)t * 30720 + (size_t)b0 * 30;
      for (int q = j; q < 480; q += 192) {
        noiseb[q]       = np[q];
        noiseb[480 + q] = nq[q];
      }
    }
    __syncthreads();  // S2

    // ---- xpre prefetch (into regs; consumed in phase C2's xo tiles).
    //      Wave's xo tile: wv>=13 -> wv ; wv<10 -> wv+16 ; else none.
    float xp[4] = {0.f, 0.f, 0.f, 0.f};
    {
      int tt_xo = (wv >= 13) ? wv : (wv < 10 ? wv + 16 : -1);
      if (tt_xo >= 0) {
        int col0 = (tt_xo - 13) * 16 + lm;
        if (col0 < 200) {
#pragma unroll
          for (int r = 0; r < 4; ++r)
            xp[r] = xpre[((size_t)t * 1024 + b0 + quad * 4 + r) * 200 + col0];
        }
      }
    }

    // ---- phase B: waves 0..7: xg = x@gru_w ; waves 8..15: hg = deter@gru_u
    //      (5 tiles/wave, B-fragments double-buffered across tiles)
    {
      const int gsel = wv >> 3, wsub = wv & 7;
      const __bf16* WF    = gsel ? guF : gwF;
      const __bf16* Abase = gsel ? &dbuf[0][0] : &xbuf[0][0];
      const int cbase = gsel ? 608 : 0;
      const int bbase = gsel ? 816 : 208;
      bf16x8 af[7];
#pragma unroll
      for (int k = 0; k < 7; ++k) af[k] = *(const bf16x8*)(Abase + lm * 232 + k * 32 + quad * 8);
      bf16x8 cur[7], nxt[7];
      {
        const __bf16* bw = WF + (size_t)wsub * 3584 + lane * 8;
#pragma unroll
        for (int k = 0; k < 7; ++k) cur[k] = *(const bf16x8*)(bw + k * 512);
      }
      for (int tt = wsub; tt < 38; tt += 8) {
        int tn = tt + 8;
        if (tn < 38) {
          const __bf16* bn = WF + (size_t)tn * 3584 + lane * 8;
#pragma unroll
          for (int k = 0; k < 7; ++k) nxt[k] = *(const bf16x8*)(bn + k * 512);
        }
        f32x4 c0 = (f32x4){0.f, 0.f, 0.f, 0.f};
        f32x4 c1 = (f32x4){0.f, 0.f, 0.f, 0.f};
        c0 = __builtin_amdgcn_mfma_f32_16x16x32_bf16(af[0], cur[0], c0, 0, 0, 0);
        c1 = __builtin_amdgcn_mfma_f32_16x16x32_bf16(af[1], cur[1], c1, 0, 0, 0);
        c0 = __builtin_amdgcn_mfma_f32_16x16x32_bf16(af[2], cur[2], c0, 0, 0, 0);
        c1 = __builtin_amdgcn_mfma_f32_16x16x32_bf16(af[3], cur[3], c1, 0, 0, 0);
        c0 = __builtin_amdgcn_mfma_f32_16x16x32_bf16(af[4], cur[4], c0, 0, 0, 0);
        c1 = __builtin_amdgcn_mfma_f32_16x16x32_bf16(af[5], cur[5], c1, 0, 0, 0);
        c0 = __builtin_amdgcn_mfma_f32_16x16x32_bf16(af[6], cur[6], c0, 0, 0, 0);
        f32x4 c = c0 + c1;
        int col = tt * 16 + lm;
        float bias = biasL[bbase + col];
#pragma unroll
        for (int r = 0; r < 4; ++r) gg[(quad * 4 + r) * 1224 + cbase + col] = (__bf16)(c[r] + bias);
#pragma unroll
        for (int k = 0; k < 7; ++k) cur[k] = nxt[k];
      }
    }
    __syncthreads();  // S3

    // ---- phase C1: GRU combine -> deter (bf16 carry) + out
    for (int idx = tid; idx < 3200; idx += 1024) {
      int m = idx / 200, d = idx - m * 200;
      const __bf16* row = gg + m * 1224;
      float xz = (float)row[d],        xr_ = (float)row[200 + d], xh = (float)row[400 + d];
      float hz = (float)row[608 + d],  hr_ = (float)row[808 + d], hh = (float)row[1008 + d];
      float z  = sigm(xz + hz);
      float rr = sigm(xr_ + hr_);
      float hc = 2.f * sigm(2.f * (xh + rr * hh)) - 1.f;   // tanh
      float dn = z * (float)dbuf[m][d] + (1.f - z) * hc;
      dbuf[m][d] = (__bf16)dn;
      size_t ob = ((size_t)(b0 + m) * 64 + t) * 580;
      out[ob + 90 + d]  = dn;
      out[ob + 380 + d] = dn;
    }
    __syncthreads();  // S4

    // ---- phase C2: x2 = elu(d@w_img2+b) ; xo = elu(d@w_obs1_d + xpre)
    {
      bf16x8 df[7];
#pragma unroll
      for (int k = 0; k < 7; ++k) df[k] = *(const bf16x8*)(&dbuf[lm][0] + k * 32 + quad * 8);
      for (int tt = wv; tt < 26; tt += 16) {
        const __bf16* bw = wcF + (size_t)tt * 3584 + lane * 8;
        bf16x8 bv[7];
#pragma unroll
        for (int k = 0; k < 7; ++k) bv[k] = *(const bf16x8*)(bw + k * 512);
        f32x4 c0 = (f32x4){0.f, 0.f, 0.f, 0.f};
        f32x4 c1 = (f32x4){0.f, 0.f, 0.f, 0.f};
        c0 = __builtin_amdgcn_mfma_f32_16x16x32_bf16(df[0], bv[0], c0, 0, 0, 0);
        c1 = __builtin_amdgcn_mfma_f32_16x16x32_bf16(df[1], bv[1], c1, 0, 0, 0);
        c0 = __builtin_amdgcn_mfma_f32_16x16x32_bf16(df[2], bv[2], c0, 0, 0, 0);
        c1 = __builtin_amdgcn_mfma_f32_16x16x32_bf16(df[3], bv[3], c1, 0, 0, 0);
        c0 = __builtin_amdgcn_mfma_f32_16x16x32_bf16(df[4], bv[4], c0, 0, 0, 0);
        c1 = __builtin_amdgcn_mfma_f32_16x16x32_bf16(df[5], bv[5], c1, 0, 0, 0);
        c0 = __builtin_amdgcn_mfma_f32_16x16x32_bf16(df[6], bv[6], c0, 0, 0, 0);
        f32x4 c = c0 + c1;
        if (tt < 13) {
          int col = tt * 16 + lm;
          float bias = biasL[1424 + col];
          if (col < 200) {
#pragma unroll
            for (int r = 0; r < 4; ++r) x2b[(quad * 4 + r) * 232 + col] = (__bf16)elu1(c[r] + bias);
          }
        } else {
          int col = (tt - 13) * 16 + lm;
          if (col < 200) {
#pragma unroll
            for (int r = 0; r < 4; ++r) {
              int m2 = quad * 4 + r;
              xob[m2 * 232 + col] = (__bf16)elu1(c[r] + xp[r]);
            }
          }
        }
      }
    }
    __syncthreads();  // S5

    // ---- phase D: heads.  waves 0..7: tile wv; tiles 0..3 <- xo, 4..7 <- x2
    if (wv < 8) {
      const __bf16* Ab = (wv < 4) ? xob : x2b;
      bf16x8 hf[7];
#pragma unroll
      for (int k = 0; k < 7; ++k) hf[k] = *(const bf16x8*)(Ab + lm * 232 + k * 32 + quad * 8);
      const __bf16* bw = whF + wv * 3584 + lane * 8;
      bf16x8 bv[7];
#pragma unroll
      for (int k = 0; k < 7; ++k) bv[k] = *(const bf16x8*)(bw + k * 512);
      f32x4 c0 = (f32x4){0.f, 0.f, 0.f, 0.f};
      f32x4 c1 = (f32x4){0.f, 0.f, 0.f, 0.f};
      c0 = __builtin_amdgcn_mfma_f32_16x16x32_bf16(hf[0], bv[0], c0, 0, 0, 0);
      c1 = __builtin_amdgcn_mfma_f32_16x16x32_bf16(hf[1], bv[1], c1, 0, 0, 0);
      c0 = __builtin_amdgcn_mfma_f32_16x16x32_bf16(hf[2], bv[2], c0, 0, 0, 0);
      c1 = __builtin_amdgcn_mfma_f32_16x16x32_bf16(hf[3], bv[3], c1, 0, 0, 0);
      c0 = __builtin_amdgcn_mfma_f32_16x16x32_bf16(hf[4], bv[4], c0, 0, 0, 0);
      c1 = __builtin_amdgcn_mfma_f32_16x16x32_bf16(hf[5], bv[5], c1, 0, 0, 0);
      c0 = __builtin_amdgcn_mfma_f32_16x16x32_bf16(hf[6], bv[6], c0, 0, 0, 0);
      f32x4 c = c0 + c1;
      int n = wv * 16 + lm;
      float bias = biasL[1632 + n];
#pragma unroll
      for (int r = 0; r < 4; ++r) headb[(quad * 4 + r) * 132 + n] = c[r] + bias;
    }
    __syncthreads();  // S6

    // ---- phase E: nonlinearities + sample + outputs + next stoch/action
    if (tid < 480) {
      int m = tid / 30, c = tid - m * 30;
      const float* hb = headb + m * 132;
      float om = hb[c], osr = hb[32 + c], pm = hb[64 + c], psr = hb[96 + c];
      float os = spls(osr);               // obs: no +0.1
      float ps = spls(psr) + 0.1f;        // img: +0.1
      float nzo = noiseb[tid];
      float nzp = noiseb[480 + tid];
      float ost = om + os * nzo;
      float pst = pm + ps * nzp;
      actin[m][c] = (__bf16)ost;          // next stoch (bf16 carry)
      size_t ob = ((size_t)(b0 + m) * 64 + t) * 580;
      out[ob + c]       = om;
      out[ob + 30 + c]  = os;
      out[ob + 60 + c]  = ost;
      out[ob + 290 + c] = pm;
      out[ob + 320 + c] = ps;
      out[ob + 350 + c] = pst;
    } else if (tid < 576 && t < 63) {
      int j = tid - 480;                   // 0..95
      int m = j / 6, k = j - m * 6;
      actin[m][30 + k] = (__bf16)action[(size_t)(b0 + m) * 384 + (t + 1) * 6 + k];
    }
    __syncthreads();  // S7
  }
}

// ---------------------------------------------------------------------------
extern "C" void kernel_launch(void* const* d_in, const int* in_sizes, int n_in,
                              void* d_out, int out_size, void* d_ws, size_t ws_size,
                              hipStream_t stream) {
  const float* embed   = (const float*)d_in[0];
  const float* action  = (const float*)d_in[1];
  const float* nzp     = (const float*)d_in[2];
  const float* nzo     = (const float*)d_in[3];
  const float* w_img1  = (const float*)d_in[4];
  const float* b_img1  = (const float*)d_in[5];
  const float* gru_w   = (const float*)d_in[6];
  const float* gru_u   = (const float*)d_in[7];
  const float* gru_b   = (const float*)d_in[8];
  const float* gru_rb  = (const float*)d_in[9];
  const float* w_img2  = (const float*)d_in[10];
  const float* b_img2  = (const float*)d_in[11];
  const float* w_imean = (const float*)d_in[12];
  const float* b_imean = (const float*)d_in[13];
  const float* w_istd  = (const float*)d_in[14];
  const float* b_istd  = (const float*)d_in[15];
  const float* w_obs1  = (const float*)d_in[16];
  const float* b_obs1  = (const float*)d_in[17];
  const float* w_omean = (const float*)d_in[18];
  const float* b_omean = (const float*)d_in[19];
  const float* w_ostd  = (const float*)d_in[20];
  const float* b_ostd  = (const float*)d_in[21];
  float* out = (float*)d_out;

  __bf16* wbf = (__bf16*)d_ws;
  float* xpre = (float*)((char*)d_ws + WS_XPRE_BYTES);

  k0_convert<<<(WS_BF_TOTAL + 255) / 256, 256, 0, stream>>>(
      w_img1, gru_w, gru_u, w_img2, w_imean, w_istd, w_obs1, w_omean, w_ostd, wbf);

  k1_embed_gemm<<<1024, 256, 0, stream>>>(embed, wbf + OFF_K1WT, b_obs1, xpre);

  k2_recurrent<<<64, 1024, 0, stream>>>(
      action, nzp, nzo,
      b_img1, gru_b, gru_rb, b_img2, b_imean, b_istd, b_omean, b_ostd,
      wbf + OFF_W1F, wbf + OFF_GWF, wbf + OFF_GUF, wbf + OFF_WCF, wbf + OFF_WHF,
      xpre, out);
}